// Round 1
// baseline (658.216 us; speedup 1.0000x reference)
//
#include <hip/hip_runtime.h>
#include <math.h>

#define NF 6
#define M2 256            // 16*16 pixels
#define TWO_PI_F 6.283185307179586f

// one block per batch element b; 256 threads
__global__ __launch_bounds__(256) void simflux_kernel(
    const float* __restrict__ params,    // (B,5)
    const float* __restrict__ mod,       // (B,6,6)
    const float* __restrict__ roipos,    // (B,2)
    const float* __restrict__ psf_ev,    // (B,256)
    const float* __restrict__ psf_deriv, // (B,256,5)
    float* __restrict__ out_mu,          // (B,6,256)
    float* __restrict__ out_deriv)       // (B,6,256,5)
{
    const unsigned b = blockIdx.x;
    const unsigned t = threadIdx.x;

    __shared__ __align__(16) float ev_s[M2];         // psf_ev tile
    __shared__ __align__(16) float d_s[2][M2 * 5];   // deriv transpose tile (double-buffered)
    __shared__ float coef_s[NF][8];  // A0,A1,A2,intensity,B0,B1,B2,S

    // ---- stage ev (coalesced dword) ----
    ev_s[t] = psf_ev[(size_t)b * M2 + t];

    // ---- per-pixel psf_deriv comps 0..2 (comps 3,4 are never used) ----
    // direct global gather, 20B stride; all 64B lines of the block's pd region
    // get touched anyway, so HBM fetch is unchanged vs staged LDS.
    const float* pdt = psf_deriv + (size_t)b * (M2 * 5) + t * 5u;
    const float pd0 = pdt[0];
    const float pd1 = pdt[1];
    const float pd2 = pdt[2];

    const float bg = params[b * 5u + 4u];   // broadcast (same addr all lanes)

    // ---- per-field modulation coefficients (lanes 0..5) ----
    if (t < NF) {
        const float x   = params[b * 5 + 0];
        const float y   = params[b * 5 + 1];
        const float z   = params[b * 5 + 2];
        const float Iph = params[b * 5 + 3];
        const float rx = roipos[b * 2 + 0];
        const float ry = roipos[b * 2 + 1];
        const float* mf = mod + ((size_t)b * NF + t) * 6;
        const float k0 = mf[0], k1 = mf[1], k2 = mf[2];
        const float depth = mf[3], phase = mf[4], relint = mf[5];

        float dot = (x + rx) * k0 + (y + ry) * k1 + z * k2;
        float r = fmodf(dot, TWO_PI_F);
        if (r < 0.f) r += TWO_PI_F;
        const float em = r - phase;
        const float sn = sinf(em);
        const float cs = cosf(em);

        const float intensity = (1.f + depth * sn) * relint;
        const float dcr = depth * cs * relint;   // * k_c -> mod_deriv_c
        const float sI  = Iph * intensity;

        coef_s[t][0] = Iph * dcr * k0;
        coef_s[t][1] = Iph * dcr * k1;
        coef_s[t][2] = Iph * dcr * k2;
        coef_s[t][3] = intensity;            // deriv_I coefficient on ev
        coef_s[t][4] = sI * (1.0f / 65.0f);  // scale folded in
        coef_s[t][5] = sI * (1.0f / 65.0f);
        coef_s[t][6] = sI * 0.001f;
        coef_s[t][7] = sI;                   // mu coefficient on ev
    }
    __syncthreads();

    // ---- mu: 6*256 floats = 384 float4 per block, pure shift/mask indexing ----
    float4* mu4 = (float4*)(out_mu + (size_t)b * (NF * M2));
    const float4* ev4 = (const float4*)ev_s;
    {
        unsigned f = t >> 6, p = t & 63u;      // 64 float4 per field
        float4 e = ev4[p];
        float s = coef_s[f][7];
        mu4[t] = make_float4(bg + s * e.x, bg + s * e.y, bg + s * e.z, bg + s * e.w);
        if (t < 128u) {
            const unsigned q = 256u + t;
            f = q >> 6; p = q & 63u;
            e = ev4[p]; s = coef_s[f][7];
            mu4[q] = make_float4(bg + s * e.x, bg + s * e.y, bg + s * e.z, bg + s * e.w);
        }
    }

    // ---- deriv: pixel-per-thread compute -> LDS transpose -> float4 stores ----
    const float evt = ev_s[t];
    float4* dv4 = (float4*)(out_deriv + (size_t)b * (NF * M2 * 5));
    #pragma unroll
    for (int f = 0; f < NF; ++f) {
        float* dd = d_s[f & 1];
        // 5 values for pixel t, field f (c=4 is the constant bg-derivative 1.0)
        const float v0 = coef_s[f][0] * evt + coef_s[f][4] * pd0;
        const float v1 = coef_s[f][1] * evt + coef_s[f][5] * pd1;
        const float v2 = coef_s[f][2] * evt + coef_s[f][6] * pd2;
        const float v3 = coef_s[f][3] * evt;
        const unsigned base = t * 5u;          // stride-5: 2 lanes/bank -> free
        dd[base + 0] = v0;
        dd[base + 1] = v1;
        dd[base + 2] = v2;
        dd[base + 3] = v3;
        dd[base + 4] = 1.0f;
        __syncthreads();                       // one barrier per field (double-buffered)
        // stream tile out: 320 float4, contiguous b128 reads + dwordx4 stores
        const float4* d4 = (const float4*)dd;
        float4* dst = dv4 + f * (M2 * 5 / 4);
        dst[t] = d4[t];
        if (t < 64u) dst[256u + t] = d4[256u + t];
        // next iteration writes the other LDS buffer -> no second barrier needed
    }
}

extern "C" void kernel_launch(void* const* d_in, const int* in_sizes, int n_in,
                              void* d_out, int out_size, void* d_ws, size_t ws_size,
                              hipStream_t stream) {
    const float* params    = (const float*)d_in[0];   // (B,5)
    const float* mod       = (const float*)d_in[1];   // (B,6,6)
    const float* roipos    = (const float*)d_in[2];   // (B,2)
    const float* psf_ev    = (const float*)d_in[3];   // (B,256)
    const float* psf_deriv = (const float*)d_in[4];   // (B,256,5)

    const int B = in_sizes[0] / 5;                    // 16384
    const size_t mu_elems = (size_t)B * NF * M2;      // 25,165,824

    float* out_mu    = (float*)d_out;
    float* out_deriv = (float*)d_out + mu_elems;

    simflux_kernel<<<B, 256, 0, stream>>>(params, mod, roipos, psf_ev, psf_deriv,
                                          out_mu, out_deriv);
}

// Round 2
// 655.643 us; speedup vs baseline: 1.0039x; 1.0039x over previous
//
#include <hip/hip_runtime.h>
#include <math.h>

#define NF 6
#define M2 256            // 16*16 pixels
#define TWO_PI_F 6.283185307179586f

typedef float f4 __attribute__((ext_vector_type(4)));

// one block per batch element b; 256 threads
__global__ __launch_bounds__(256) void simflux_kernel(
    const float* __restrict__ params,    // (B,5)
    const float* __restrict__ mod,       // (B,6,6)
    const float* __restrict__ roipos,    // (B,2)
    const float* __restrict__ psf_ev,    // (B,256)
    const float* __restrict__ psf_deriv, // (B,256,5)
    float* __restrict__ out_mu,          // (B,6,256)
    float* __restrict__ out_deriv)       // (B,6,256,5)
{
    const unsigned b = blockIdx.x;
    const unsigned t = threadIdx.x;

    __shared__ __align__(16) float ev_s[M2];         // psf_ev tile
    __shared__ __align__(16) float d_s[2][M2 * 5];   // deriv transpose tile (double-buffered)
    __shared__ float coef_s[NF][8];  // A0,A1,A2,intensity,B0,B1,B2,S

    // ---- stage ev (coalesced dword, nontemporal: zero reuse across blocks) ----
    ev_s[t] = __builtin_nontemporal_load(psf_ev + (size_t)b * M2 + t);

    // ---- per-pixel psf_deriv comps 0..2 (comps 3,4 are never used) ----
    // streaming, read-once: nontemporal so these 84 MB don't pollute L2
    const float* pdt = psf_deriv + (size_t)b * (M2 * 5) + t * 5u;
    const float pd0 = __builtin_nontemporal_load(pdt + 0);
    const float pd1 = __builtin_nontemporal_load(pdt + 1);
    const float pd2 = __builtin_nontemporal_load(pdt + 2);

    const float bg = params[b * 5u + 4u];   // broadcast (same addr all lanes)

    // ---- per-field modulation coefficients (lanes 0..5) ----
    if (t < NF) {
        const float x   = params[b * 5 + 0];
        const float y   = params[b * 5 + 1];
        const float z   = params[b * 5 + 2];
        const float Iph = params[b * 5 + 3];
        const float rx = roipos[b * 2 + 0];
        const float ry = roipos[b * 2 + 1];
        const float* mf = mod + ((size_t)b * NF + t) * 6;
        const float k0 = mf[0], k1 = mf[1], k2 = mf[2];
        const float depth = mf[3], phase = mf[4], relint = mf[5];

        float dot = (x + rx) * k0 + (y + ry) * k1 + z * k2;
        float r = fmodf(dot, TWO_PI_F);
        if (r < 0.f) r += TWO_PI_F;
        const float em = r - phase;
        const float sn = sinf(em);
        const float cs = cosf(em);

        const float intensity = (1.f + depth * sn) * relint;
        const float dcr = depth * cs * relint;   // * k_c -> mod_deriv_c
        const float sI  = Iph * intensity;

        coef_s[t][0] = Iph * dcr * k0;
        coef_s[t][1] = Iph * dcr * k1;
        coef_s[t][2] = Iph * dcr * k2;
        coef_s[t][3] = intensity;            // deriv_I coefficient on ev
        coef_s[t][4] = sI * (1.0f / 65.0f);  // scale folded in
        coef_s[t][5] = sI * (1.0f / 65.0f);
        coef_s[t][6] = sI * 0.001f;
        coef_s[t][7] = sI;                   // mu coefficient on ev
    }
    __syncthreads();

    // ---- mu: 6*256 floats = 384 float4 per block, nontemporal stores ----
    f4* mu4 = (f4*)(out_mu + (size_t)b * (NF * M2));
    const f4* ev4 = (const f4*)ev_s;
    {
        unsigned f = t >> 6, p = t & 63u;      // 64 float4 per field
        f4 e = ev4[p];
        float s = coef_s[f][7];
        f4 v = { bg + s * e.x, bg + s * e.y, bg + s * e.z, bg + s * e.w };
        __builtin_nontemporal_store(v, mu4 + t);
        if (t < 128u) {
            const unsigned q = 256u + t;
            f = q >> 6; p = q & 63u;
            e = ev4[p]; s = coef_s[f][7];
            f4 w = { bg + s * e.x, bg + s * e.y, bg + s * e.z, bg + s * e.w };
            __builtin_nontemporal_store(w, mu4 + q);
        }
    }

    // ---- deriv: pixel-per-thread compute -> LDS transpose -> nt float4 stores ----
    const float evt = ev_s[t];
    f4* dv4 = (f4*)(out_deriv + (size_t)b * (NF * M2 * 5));
    #pragma unroll
    for (int f = 0; f < NF; ++f) {
        float* dd = d_s[f & 1];
        // 5 values for pixel t, field f (c=4 is the constant bg-derivative 1.0)
        const float v0 = coef_s[f][0] * evt + coef_s[f][4] * pd0;
        const float v1 = coef_s[f][1] * evt + coef_s[f][5] * pd1;
        const float v2 = coef_s[f][2] * evt + coef_s[f][6] * pd2;
        const float v3 = coef_s[f][3] * evt;
        const unsigned base = t * 5u;          // stride-5: 2 lanes/bank -> free
        dd[base + 0] = v0;
        dd[base + 1] = v1;
        dd[base + 2] = v2;
        dd[base + 3] = v3;
        dd[base + 4] = 1.0f;
        __syncthreads();                       // one barrier per field (double-buffered)
        // stream tile out: 320 float4, contiguous b128 reads + nt dwordx4 stores
        const f4* d4 = (const f4*)dd;
        f4* dst = dv4 + f * (M2 * 5 / 4);
        __builtin_nontemporal_store(d4[t], dst + t);
        if (t < 64u) __builtin_nontemporal_store(d4[256u + t], dst + 256u + t);
        // next iteration writes the other LDS buffer -> no second barrier needed
    }
}

extern "C" void kernel_launch(void* const* d_in, const int* in_sizes, int n_in,
                              void* d_out, int out_size, void* d_ws, size_t ws_size,
                              hipStream_t stream) {
    const float* params    = (const float*)d_in[0];   // (B,5)
    const float* mod       = (const float*)d_in[1];   // (B,6,6)
    const float* roipos    = (const float*)d_in[2];   // (B,2)
    const float* psf_ev    = (const float*)d_in[3];   // (B,256)
    const float* psf_deriv = (const float*)d_in[4];   // (B,256,5)

    const int B = in_sizes[0] / 5;                    // 16384
    const size_t mu_elems = (size_t)B * NF * M2;      // 25,165,824

    float* out_mu    = (float*)d_out;
    float* out_deriv = (float*)d_out + mu_elems;

    simflux_kernel<<<B, 256, 0, stream>>>(params, mod, roipos, psf_ev, psf_deriv,
                                          out_mu, out_deriv);
}